// Round 5
// baseline (43.787 us; speedup 1.0000x reference)
//
#include <hip/hip_runtime.h>
#include <math.h>

#define BWALK 4096
#define NS 64
#define DD 256
#define NE 16
#define NSLOT 128
#define CHUNK 512   // walkers per orbitals block

typedef __attribute__((ext_vector_type(4))) float f32x4;
typedef __attribute__((ext_vector_type(8))) short s16x8;

union Frag  { s16x8 v; unsigned u[4]; uint4 q; };

__device__ inline unsigned rne_bf16(float x) {
    unsigned u = __float_as_uint(x);
    return (u + 0x7fffu + ((u >> 16) & 1u)) >> 16;
}
__device__ inline float bf16_to_f(unsigned h) { return __uint_as_float(h << 16); }

// ---------- kernel 0: M -> fragment-ordered bf16 hi/lo (1 MB + 1 MB) ----------
// Layout: uint4 index (n*8 + kc)*64 + lane, lane = kg*16 + e;
// word t of that uint4 = bf16(M[n][kc*32+kg*8+2t][e]) | bf16(M[n][...+2t+1][e])<<16
__global__ __launch_bounds__(256) void convert_m_kernel(
    const float* __restrict__ Mup,
    const float* __restrict__ Mdn,
    uint4* __restrict__ Mhi,
    uint4* __restrict__ Mlo)
{
    const int t = blockIdx.x * 256 + threadIdx.x;   // 0 .. 128*8*64-1
    const int n    = t >> 9;
    const int kc   = (t >> 6) & 7;
    const int lane = t & 63;
    const int kg = lane >> 4;
    const int e  = lane & 15;

    const float* Msrc = (n < NS ? Mup : Mdn) + (size_t)(n & (NS - 1)) * (DD * NE);

    unsigned h[8], l[8];
    #pragma unroll
    for (int j = 0; j < 8; ++j) {
        const int k = kc * 32 + kg * 8 + j;
        const float f = Msrc[k * 16 + e];
        const unsigned hh = rne_bf16(f);
        h[j] = hh;
        l[j] = rne_bf16(f - bf16_to_f(hh));
    }
    uint4 vh, vl;
    vh.x = h[0] | (h[1] << 16); vh.y = h[2] | (h[3] << 16);
    vh.z = h[4] | (h[5] << 16); vh.w = h[6] | (h[7] << 16);
    vl.x = l[0] | (l[1] << 16); vl.y = l[2] | (l[3] << 16);
    vl.z = l[4] | (l[5] << 16); vl.w = l[6] | (l[7] << 16);
    Mhi[t] = vh;
    Mlo[t] = vl;
}

// ---------- kernel 1: per-(slot, walker-chunk) gathered orbital MFMA ----------
__global__ __launch_bounds__(256) void orbitals_kernel(
    const float* __restrict__ y,
    const int* __restrict__ R,
    const uint4* __restrict__ Mhi,
    const uint4* __restrict__ Mlo,
    float* __restrict__ A)
{
    const int n   = blockIdx.y;            // orbital slot 0..127
    const int b0  = blockIdx.x * CHUNK;    // first walker of this chunk
    const int tid = threadIdx.x;
    const int lane = tid & 63;
    const int wv   = tid >> 6;

    __shared__ int sCode[CHUNK];           // 2 KB compacted (b<<4)|i codes
    __shared__ int wsum[4];

    // ---- find matches: walker b matches iff n is among R[b][0..15] ----
    int m[2];
    int cnt = 0;
    #pragma unroll
    for (int q = 0; q < 2; ++q) {
        const int b = b0 + tid * 2 + q;
        const int4* rp = (const int4*)(R + (size_t)b * NE);
        int mi = -1;
        #pragma unroll
        for (int t4 = 0; t4 < 4; ++t4) {
            const int4 r4 = rp[t4];
            if (r4.x == n) mi = t4 * 4 + 0;
            if (r4.y == n) mi = t4 * 4 + 1;
            if (r4.z == n) mi = t4 * 4 + 2;
            if (r4.w == n) mi = t4 * 4 + 3;
        }
        m[q] = mi;
        cnt += (mi >= 0) ? 1 : 0;
    }

    // wave-inclusive scan + cross-wave offsets
    int incl = cnt;
    #pragma unroll
    for (int off = 1; off < 64; off <<= 1) {
        const int x = __shfl_up(incl, off, 64);
        if (lane >= off) incl += x;
    }
    if (lane == 63) wsum[wv] = incl;
    __syncthreads();
    int base = incl - cnt;
    #pragma unroll
    for (int w = 0; w < 3; ++w) if (w < wv) base += wsum[w];
    const int total = wsum[0] + wsum[1] + wsum[2] + wsum[3];
    {
        int p = base;
        #pragma unroll
        for (int q = 0; q < 2; ++q) {
            if (m[q] >= 0) {
                const int b = b0 + tid * 2 + q;
                sCode[p++] = (b << 4) | m[q];
            }
        }
    }
    __syncthreads();

    if (total == 0) return;

    const int e  = lane & 15;
    const int kg = lane >> 4;
    const int slot = n & (NS - 1);
    const uint4* bhp = Mhi + ((size_t)n * 8) * 64 + lane;   // + kc*64
    const uint4* blp = Mlo + ((size_t)n * 8) * 64 + lane;

    for (int g = wv * 16; g < total; g += 64) {
        const int me = g + e;
        const int code = sCode[me < total ? me : (total - 1)];  // (b<<4)|i
        const int b = code >> 4;
        const float* yrow = y + ((size_t)b * NS + slot) * DD + kg * 8;

        // issue all gathers + B-frag loads up front (MLP)
        f32x4 v[8][2];
        #pragma unroll
        for (int kc = 0; kc < 8; ++kc) {
            const f32x4* p = (const f32x4*)(yrow + kc * 32);
            v[kc][0] = p[0];
            v[kc][1] = p[1];
        }
        Frag BH[8], BL[8];
        #pragma unroll
        for (int kc = 0; kc < 8; ++kc) {
            BH[kc].q = bhp[kc * 64];
            BL[kc].q = blp[kc * 64];
        }

        f32x4 acc0 = {0.f, 0.f, 0.f, 0.f};
        f32x4 acc1 = {0.f, 0.f, 0.f, 0.f};
        f32x4 acc2 = {0.f, 0.f, 0.f, 0.f};
        #pragma unroll
        for (int kc = 0; kc < 8; ++kc) {
            Frag ahi, alo;
            #pragma unroll
            for (int t = 0; t < 4; ++t) {
                const float f0 = v[kc][t >> 1][(t & 1) * 2];
                const float f1 = v[kc][t >> 1][(t & 1) * 2 + 1];
                const unsigned h0 = rne_bf16(f0), h1 = rne_bf16(f1);
                ahi.u[t] = h0 | (h1 << 16);
                const unsigned l0 = rne_bf16(f0 - bf16_to_f(h0));
                const unsigned l1 = rne_bf16(f1 - bf16_to_f(h1));
                alo.u[t] = l0 | (l1 << 16);
            }
            acc0 = __builtin_amdgcn_mfma_f32_16x16x32_bf16(ahi.v, BH[kc].v, acc0, 0, 0, 0);
            acc1 = __builtin_amdgcn_mfma_f32_16x16x32_bf16(ahi.v, BL[kc].v, acc1, 0, 0, 0);
            acc2 = __builtin_amdgcn_mfma_f32_16x16x32_bf16(alo.v, BH[kc].v, acc2, 0, 0, 0);
        }
        const f32x4 acc = acc0 + (acc1 + acc2);

        // C layout: col = lane&15, row = (lane>>4)*4 + r
        #pragma unroll
        for (int r = 0; r < 4; ++r) {
            const int j = kg * 4 + r;
            const int jcode = __shfl(code, j, 16);
            if (g + j < total) A[(size_t)jcode * NE + e] = acc[r];
        }
    }
}

// ---------- kernel 2: batched 16x16 LU slogdet (4 walkers / wave) ----------
__global__ __launch_bounds__(256) void lu_det_kernel(
    const float* __restrict__ A, float* __restrict__ out, int mode)
{
    const int tid = threadIdx.x;
    const int w = blockIdx.x * 16 + (tid >> 4);
    const int lane = tid & 15;

    float a[NE];
    {
        const f32x4* p = (const f32x4*)(A + ((size_t)w * NE + lane) * NE);
        #pragma unroll
        for (int q = 0; q < 4; ++q) {
            const f32x4 vv = p[q];
            a[q * 4 + 0] = vv[0]; a[q * 4 + 1] = vv[1];
            a[q * 4 + 2] = vv[2]; a[q * 4 + 3] = vv[3];
        }
    }

    unsigned used = 0u;
    float logabs = 0.0f;
    int neg = 0;
    int perm[NE];

    #pragma unroll
    for (int k = 0; k < NE; ++k) {
        float v = ((used >> lane) & 1u) ? -1.0f : fabsf(a[k]);
        int bi = lane;
        #pragma unroll
        for (int off = 8; off > 0; off >>= 1) {
            const float ov = __shfl_xor(v, off, 16);
            const int   oi = __shfl_xor(bi, off, 16);
            if (ov > v || (ov == v && oi < bi)) { v = ov; bi = oi; }
        }
        const int p = bi;
        perm[k] = p;
        const float pivval = __shfl(a[k], p, 16);
        const bool active = (((used >> lane) & 1u) == 0u) && (lane != p);
        const float mlt = active ? (a[k] / pivval) : 0.0f;
        #pragma unroll
        for (int ee = k + 1; ee < NE; ++ee) {
            const float pe = __shfl(a[ee], p, 16);
            a[ee] = fmaf(-mlt, pe, a[ee]);
        }
        used |= (1u << p);
        logabs += logf(fabsf(pivval));
        neg ^= (pivval < 0.0f) ? 1 : 0;
    }

    int inv = 0;
    #pragma unroll
    for (int k1 = 0; k1 < NE; ++k1) {
        #pragma unroll
        for (int k2 = k1 + 1; k2 < NE; ++k2)
            inv ^= (perm[k1] > perm[k2]) ? 1 : 0;
    }
    neg ^= inv;

    if (lane == 0) {
        float re = logabs;
        float im = neg ? 3.14159274101257324f : 0.0f;
        if (__builtin_isnan(re)) { re = -INFINITY; im = 0.0f; }
        else if (re == -INFINITY) { im = 0.0f; }
        if (mode == 0) { out[2 * w] = re; out[2 * w + 1] = im; }
        else           { out[w] = re; }
    }
}

// ---------- fallback: round-2 fused kernel (passing, 61.5 us) ----------
__global__ __launch_bounds__(256) void outputheaddet_kernel(
    const float* __restrict__ y,
    const float* __restrict__ Mup,
    const float* __restrict__ Mdn,
    const int* __restrict__ R,
    float* __restrict__ out,
    int mode)
{
    const int b = blockIdx.x;
    const int tid = threadIdx.x;

    __shared__ int   sR[NE];
    __shared__ float sY[NE][DD];
    __shared__ float sA[NE][NE + 1];

    if (tid < NE) sR[tid] = R[b * NE + tid];
    __syncthreads();

    {
        const int i  = tid >> 4;
        const int d0 = (tid & 15) * 16;
        const int n    = sR[i];
        const int slot = n & (NS - 1);
        const float4* yp = reinterpret_cast<const float4*>(
            y + (((size_t)b * NS + slot) * DD + d0));
        float4 v0 = yp[0], v1 = yp[1], v2 = yp[2], v3 = yp[3];
        float4* dst = reinterpret_cast<float4*>(&sY[i][d0]);
        dst[0] = v0; dst[1] = v1; dst[2] = v2; dst[3] = v3;
    }
    __syncthreads();

    {
        const int i = tid >> 4;
        const int e = tid & 15;
        const int n    = sR[i];
        const int slot = n & (NS - 1);
        const float* Mp = (n < NS ? Mup : Mdn) + (size_t)slot * (DD * NE) + e;
        float acc = 0.0f;
        #pragma unroll 8
        for (int d = 0; d < DD; ++d)
            acc = fmaf(sY[i][d], Mp[(size_t)d * NE], acc);
        sA[i][e] = acc;
    }
    __syncthreads();

    if (tid >= NE) return;

    const int lane = tid;
    float a[NE];
    #pragma unroll
    for (int e = 0; e < NE; ++e) a[e] = sA[lane][e];

    unsigned used = 0u;
    float logabs = 0.0f;
    int neg = 0;
    int perm[NE];

    #pragma unroll
    for (int k = 0; k < NE; ++k) {
        float v = ((used >> lane) & 1u) ? -1.0f : fabsf(a[k]);
        int bi = lane;
        #pragma unroll
        for (int off = 8; off > 0; off >>= 1) {
            float ov = __shfl_xor(v, off, 16);
            int   oi = __shfl_xor(bi, off, 16);
            if (ov > v || (ov == v && oi < bi)) { v = ov; bi = oi; }
        }
        const int p = bi;
        perm[k] = p;
        const float pivval = __shfl(a[k], p, 16);
        const bool active = (((used >> lane) & 1u) == 0u) && (lane != p);
        const float mlt = active ? (a[k] / pivval) : 0.0f;
        #pragma unroll
        for (int e = k + 1; e < NE; ++e) {
            const float pe = __shfl(a[e], p, 16);
            a[e] = fmaf(-mlt, pe, a[e]);
        }
        used |= (1u << p);
        logabs += logf(fabsf(pivval));
        neg ^= (pivval < 0.0f) ? 1 : 0;
    }

    int inv = 0;
    #pragma unroll
    for (int k1 = 0; k1 < NE; ++k1) {
        #pragma unroll
        for (int k2 = k1 + 1; k2 < NE; ++k2)
            inv ^= (perm[k1] > perm[k2]) ? 1 : 0;
    }
    neg ^= inv;

    if (lane == 0) {
        float re = logabs;
        float im = neg ? 3.14159274101257324f : 0.0f;
        if (__builtin_isnan(re)) { re = -INFINITY; im = 0.0f; }
        else if (re == -INFINITY) { im = 0.0f; }
        if (mode == 0) { out[2 * b] = re; out[2 * b + 1] = im; }
        else           { out[b] = re; }
    }
}

extern "C" void kernel_launch(void* const* d_in, const int* in_sizes, int n_in,
                              void* d_out, int out_size, void* d_ws, size_t ws_size,
                              hipStream_t stream) {
    const float* y   = (const float*)d_in[0];
    const float* Mup = (const float*)d_in[1];
    const float* Mdn = (const float*)d_in[2];
    const int*   R   = (const int*)d_in[3];
    float* out = (float*)d_out;

    const int mode = (out_size >= 2 * BWALK) ? 0 : 1;

    const size_t frag_bytes = (size_t)NSLOT * 8 * 64 * 16;           // 1 MB each
    const size_t off_Mlo = frag_bytes;
    const size_t off_A   = 2 * frag_bytes;
    const size_t need    = off_A + (size_t)BWALK * NE * NE * sizeof(float);  // 6 MB

    if (ws_size >= need) {
        uint4* Mhi = (uint4*)d_ws;
        uint4* Mlo = (uint4*)((char*)d_ws + off_Mlo);
        float* A   = (float*)((char*)d_ws + off_A);

        hipLaunchKernelGGL(convert_m_kernel, dim3(NSLOT * 8 * 64 / 256), dim3(256), 0, stream,
                           Mup, Mdn, Mhi, Mlo);
        hipLaunchKernelGGL(orbitals_kernel, dim3(BWALK / CHUNK, NSLOT), dim3(256), 0, stream,
                           y, R, Mhi, Mlo, A);
        hipLaunchKernelGGL(lu_det_kernel, dim3(BWALK / 16), dim3(256), 0, stream,
                           A, out, mode);
    } else {
        hipLaunchKernelGGL(outputheaddet_kernel, dim3(BWALK), dim3(256), 0, stream,
                           y, Mup, Mdn, R, out, mode);
    }
}

// Round 6
// 41.683 us; speedup vs baseline: 1.0505x; 1.0505x over previous
//
#include <hip/hip_runtime.h>
#include <math.h>

#define BWALK 4096
#define NS 64
#define DD 256
#define NE 16
#define NSLOT 128
#define CHUNK 512            // walkers per orbitals block
#define ROWB 528             // LDS row stride bytes (512B bf16 row + 16B pad)

typedef __attribute__((ext_vector_type(4))) float f32x4;
typedef __attribute__((ext_vector_type(8))) short s16x8;

union Frag  { s16x8 v; unsigned u[4]; uint4 q; };

__device__ inline unsigned rne_bf16(float x) {
    unsigned u = __float_as_uint(x);
    return (u + 0x7fffu + ((u >> 16) & 1u)) >> 16;
}
__device__ inline float bf16_to_f(unsigned h) { return __uint_as_float(h << 16); }

// ---------- kernel 0: M -> fragment-ordered bf16 hi/lo (1 MB + 1 MB) ----------
__global__ __launch_bounds__(256) void convert_m_kernel(
    const float* __restrict__ Mup,
    const float* __restrict__ Mdn,
    uint4* __restrict__ Mhi,
    uint4* __restrict__ Mlo)
{
    const int t = blockIdx.x * 256 + threadIdx.x;   // 0 .. 128*8*64-1
    const int n    = t >> 9;
    const int kc   = (t >> 6) & 7;
    const int lane = t & 63;
    const int kg = lane >> 4;
    const int e  = lane & 15;

    const float* Msrc = (n < NS ? Mup : Mdn) + (size_t)(n & (NS - 1)) * (DD * NE);

    unsigned h[8], l[8];
    #pragma unroll
    for (int j = 0; j < 8; ++j) {
        const int k = kc * 32 + kg * 8 + j;
        const float f = Msrc[k * 16 + e];
        const unsigned hh = rne_bf16(f);
        h[j] = hh;
        l[j] = rne_bf16(f - bf16_to_f(hh));
    }
    uint4 vh, vl;
    vh.x = h[0] | (h[1] << 16); vh.y = h[2] | (h[3] << 16);
    vh.z = h[4] | (h[5] << 16); vh.w = h[6] | (h[7] << 16);
    vl.x = l[0] | (l[1] << 16); vl.y = l[2] | (l[3] << 16);
    vl.z = l[4] | (l[5] << 16); vl.w = l[6] | (l[7] << 16);
    Mhi[t] = vh;
    Mlo[t] = vl;
}

// ---------- kernel 1: slot-major gathered orbital MFMA, wave-coalesced rows ----------
// grid (slot, chunk): XCD = slot%8 -> per-XCD M-frag set (16 slots, 512KB) L2-resident.
__global__ __launch_bounds__(256) void orbitals_kernel(
    const float* __restrict__ y,
    const int* __restrict__ R,
    const uint4* __restrict__ Mhi,
    const uint4* __restrict__ Mlo,
    float* __restrict__ A)
{
    const int n   = blockIdx.x;            // orbital slot 0..127
    const int b0  = blockIdx.y * CHUNK;    // first walker of this chunk
    const int tid = threadIdx.x;
    const int lane = tid & 63;
    const int wv   = tid >> 6;

    // 4 waves x (hi plane 16x528 + lo plane 16x528) = 67.5 KB, wave-private
    __shared__ __align__(16) unsigned char sY[4 * 2 * 16 * ROWB];
    __shared__ int sCode[CHUNK];           // compacted (b<<4)|i codes
    __shared__ int wsum[4];

    // ---- find matches: walker b matches iff n is among R[b][0..15] ----
    int m[2];
    int cnt = 0;
    #pragma unroll
    for (int q = 0; q < 2; ++q) {
        const int b = b0 + tid * 2 + q;
        const int4* rp = (const int4*)(R + (size_t)b * NE);
        int mi = -1;
        #pragma unroll
        for (int t4 = 0; t4 < 4; ++t4) {
            const int4 r4 = rp[t4];
            if (r4.x == n) mi = t4 * 4 + 0;
            if (r4.y == n) mi = t4 * 4 + 1;
            if (r4.z == n) mi = t4 * 4 + 2;
            if (r4.w == n) mi = t4 * 4 + 3;
        }
        m[q] = mi;
        cnt += (mi >= 0) ? 1 : 0;
    }

    int incl = cnt;
    #pragma unroll
    for (int off = 1; off < 64; off <<= 1) {
        const int x = __shfl_up(incl, off, 64);
        if (lane >= off) incl += x;
    }
    if (lane == 63) wsum[wv] = incl;
    __syncthreads();
    int base = incl - cnt;
    #pragma unroll
    for (int w = 0; w < 3; ++w) if (w < wv) base += wsum[w];
    const int total = wsum[0] + wsum[1] + wsum[2] + wsum[3];
    {
        int p = base;
        #pragma unroll
        for (int q = 0; q < 2; ++q) {
            if (m[q] >= 0) {
                const int b = b0 + tid * 2 + q;
                sCode[p++] = (b << 4) | m[q];
            }
        }
    }
    __syncthreads();

    if (total == 0) return;

    const int e  = lane & 15;
    const int kg = lane >> 4;
    const int slot = n & (NS - 1);
    const uint4* bhp = Mhi + ((size_t)n * 8) * 64 + lane;   // + kc*64
    const uint4* blp = Mlo + ((size_t)n * 8) * 64 + lane;

    char* waveBase = (char*)sY + wv * (2 * 16 * ROWB);
    char* hiBase = waveBase;
    char* loBase = waveBase + 16 * ROWB;

    for (int g = wv * 16; g < total; g += 64) {
        // B fragments for this slot (L2-resident, XCD-local)
        Frag BH[8], BL[8];
        #pragma unroll
        for (int kc = 0; kc < 8; ++kc) {
            BH[kc].q = bhp[kc * 64];
            BL[kc].q = blp[kc * 64];
        }

        // ---- stage 16 rows; each row = ONE fully-coalesced 1KB wave load ----
        f32x4 vv[16];
        #pragma unroll
        for (int r = 0; r < 16; ++r) {
            const int idx = g + r;
            const int code = sCode[idx < total ? idx : (total - 1)];
            const float* row = y + ((size_t)(code >> 4) * NS + slot) * DD;
            vv[r] = ((const f32x4*)row)[lane];
        }
        #pragma unroll
        for (int r = 0; r < 16; ++r) {
            unsigned h[4], l[4];
            #pragma unroll
            for (int j = 0; j < 4; ++j) {
                const float f = vv[r][j];
                h[j] = rne_bf16(f);
                l[j] = rne_bf16(f - bf16_to_f(h[j]));
            }
            uint2 hw, lw;
            hw.x = h[0] | (h[1] << 16); hw.y = h[2] | (h[3] << 16);
            lw.x = l[0] | (l[1] << 16); lw.y = l[2] | (l[3] << 16);
            *(uint2*)(hiBase + r * ROWB + lane * 8) = hw;
            *(uint2*)(loBase + r * ROWB + lane * 8) = lw;
        }
        // wave-private region: compiler-inserted lgkmcnt orders write->read; no barrier

        const int gme = g + e;
        const int mycode = sCode[gme < total ? gme : (total - 1)];

        f32x4 acc0 = {0.f, 0.f, 0.f, 0.f};
        f32x4 acc1 = {0.f, 0.f, 0.f, 0.f};
        f32x4 acc2 = {0.f, 0.f, 0.f, 0.f};
        #pragma unroll
        for (int kc = 0; kc < 8; ++kc) {
            Frag ahi, alo;
            ahi.q = *(const uint4*)(hiBase + e * ROWB + kg * 16 + kc * 64);
            alo.q = *(const uint4*)(loBase + e * ROWB + kg * 16 + kc * 64);
            acc0 = __builtin_amdgcn_mfma_f32_16x16x32_bf16(ahi.v, BH[kc].v, acc0, 0, 0, 0);
            acc1 = __builtin_amdgcn_mfma_f32_16x16x32_bf16(ahi.v, BL[kc].v, acc1, 0, 0, 0);
            acc2 = __builtin_amdgcn_mfma_f32_16x16x32_bf16(alo.v, BH[kc].v, acc2, 0, 0, 0);
        }
        const f32x4 acc = acc0 + (acc1 + acc2);

        // C layout: col = lane&15, row = (lane>>4)*4 + r
        #pragma unroll
        for (int r = 0; r < 4; ++r) {
            const int j = kg * 4 + r;
            const int jcode = __shfl(mycode, j, 16);
            if (g + j < total) A[(size_t)jcode * NE + e] = acc[r];
        }
    }
}

// ---------- kernel 2: batched 16x16 LU slogdet (4 walkers / wave) ----------
__global__ __launch_bounds__(256) void lu_det_kernel(
    const float* __restrict__ A, float* __restrict__ out, int mode)
{
    const int tid = threadIdx.x;
    const int w = blockIdx.x * 16 + (tid >> 4);
    const int lane = tid & 15;

    float a[NE];
    {
        const f32x4* p = (const f32x4*)(A + ((size_t)w * NE + lane) * NE);
        #pragma unroll
        for (int q = 0; q < 4; ++q) {
            const f32x4 vv = p[q];
            a[q * 4 + 0] = vv[0]; a[q * 4 + 1] = vv[1];
            a[q * 4 + 2] = vv[2]; a[q * 4 + 3] = vv[3];
        }
    }

    unsigned used = 0u;
    float logabs = 0.0f;
    int neg = 0;
    int perm[NE];

    #pragma unroll
    for (int k = 0; k < NE; ++k) {
        float v = ((used >> lane) & 1u) ? -1.0f : fabsf(a[k]);
        int bi = lane;
        #pragma unroll
        for (int off = 8; off > 0; off >>= 1) {
            const float ov = __shfl_xor(v, off, 16);
            const int   oi = __shfl_xor(bi, off, 16);
            if (ov > v || (ov == v && oi < bi)) { v = ov; bi = oi; }
        }
        const int p = bi;
        perm[k] = p;
        const float pivval = __shfl(a[k], p, 16);
        const bool active = (((used >> lane) & 1u) == 0u) && (lane != p);
        const float mlt = active ? (a[k] / pivval) : 0.0f;
        #pragma unroll
        for (int ee = k + 1; ee < NE; ++ee) {
            const float pe = __shfl(a[ee], p, 16);
            a[ee] = fmaf(-mlt, pe, a[ee]);
        }
        used |= (1u << p);
        logabs += logf(fabsf(pivval));
        neg ^= (pivval < 0.0f) ? 1 : 0;
    }

    int inv = 0;
    #pragma unroll
    for (int k1 = 0; k1 < NE; ++k1) {
        #pragma unroll
        for (int k2 = k1 + 1; k2 < NE; ++k2)
            inv ^= (perm[k1] > perm[k2]) ? 1 : 0;
    }
    neg ^= inv;

    if (lane == 0) {
        float re = logabs;
        float im = neg ? 3.14159274101257324f : 0.0f;
        if (__builtin_isnan(re)) { re = -INFINITY; im = 0.0f; }
        else if (re == -INFINITY) { im = 0.0f; }
        if (mode == 0) { out[2 * w] = re; out[2 * w + 1] = im; }
        else           { out[w] = re; }
    }
}

// ---------- fallback: round-2 fused kernel (passing, 61.5 us) ----------
__global__ __launch_bounds__(256) void outputheaddet_kernel(
    const float* __restrict__ y,
    const float* __restrict__ Mup,
    const float* __restrict__ Mdn,
    const int* __restrict__ R,
    float* __restrict__ out,
    int mode)
{
    const int b = blockIdx.x;
    const int tid = threadIdx.x;

    __shared__ int   sR[NE];
    __shared__ float sYf[NE][DD];
    __shared__ float sA[NE][NE + 1];

    if (tid < NE) sR[tid] = R[b * NE + tid];
    __syncthreads();

    {
        const int i  = tid >> 4;
        const int d0 = (tid & 15) * 16;
        const int n    = sR[i];
        const int slot = n & (NS - 1);
        const float4* yp = reinterpret_cast<const float4*>(
            y + (((size_t)b * NS + slot) * DD + d0));
        float4 v0 = yp[0], v1 = yp[1], v2 = yp[2], v3 = yp[3];
        float4* dst = reinterpret_cast<float4*>(&sYf[i][d0]);
        dst[0] = v0; dst[1] = v1; dst[2] = v2; dst[3] = v3;
    }
    __syncthreads();

    {
        const int i = tid >> 4;
        const int e = tid & 15;
        const int n    = sR[i];
        const int slot = n & (NS - 1);
        const float* Mp = (n < NS ? Mup : Mdn) + (size_t)slot * (DD * NE) + e;
        float acc = 0.0f;
        #pragma unroll 8
        for (int d = 0; d < DD; ++d)
            acc = fmaf(sYf[i][d], Mp[(size_t)d * NE], acc);
        sA[i][e] = acc;
    }
    __syncthreads();

    if (tid >= NE) return;

    const int lane = tid;
    float a[NE];
    #pragma unroll
    for (int e = 0; e < NE; ++e) a[e] = sA[lane][e];

    unsigned used = 0u;
    float logabs = 0.0f;
    int neg = 0;
    int perm[NE];

    #pragma unroll
    for (int k = 0; k < NE; ++k) {
        float v = ((used >> lane) & 1u) ? -1.0f : fabsf(a[k]);
        int bi = lane;
        #pragma unroll
        for (int off = 8; off > 0; off >>= 1) {
            float ov = __shfl_xor(v, off, 16);
            int   oi = __shfl_xor(bi, off, 16);
            if (ov > v || (ov == v && oi < bi)) { v = ov; bi = oi; }
        }
        const int p = bi;
        perm[k] = p;
        const float pivval = __shfl(a[k], p, 16);
        const bool active = (((used >> lane) & 1u) == 0u) && (lane != p);
        const float mlt = active ? (a[k] / pivval) : 0.0f;
        #pragma unroll
        for (int e = k + 1; e < NE; ++e) {
            const float pe = __shfl(a[e], p, 16);
            a[e] = fmaf(-mlt, pe, a[e]);
        }
        used |= (1u << p);
        logabs += logf(fabsf(pivval));
        neg ^= (pivval < 0.0f) ? 1 : 0;
    }

    int inv = 0;
    #pragma unroll
    for (int k1 = 0; k1 < NE; ++k1) {
        #pragma unroll
        for (int k2 = k1 + 1; k2 < NE; ++k2)
            inv ^= (perm[k1] > perm[k2]) ? 1 : 0;
    }
    neg ^= inv;

    if (lane == 0) {
        float re = logabs;
        float im = neg ? 3.14159274101257324f : 0.0f;
        if (__builtin_isnan(re)) { re = -INFINITY; im = 0.0f; }
        else if (re == -INFINITY) { im = 0.0f; }
        if (mode == 0) { out[2 * b] = re; out[2 * b + 1] = im; }
        else           { out[b] = re; }
    }
}

extern "C" void kernel_launch(void* const* d_in, const int* in_sizes, int n_in,
                              void* d_out, int out_size, void* d_ws, size_t ws_size,
                              hipStream_t stream) {
    const float* y   = (const float*)d_in[0];
    const float* Mup = (const float*)d_in[1];
    const float* Mdn = (const float*)d_in[2];
    const int*   R   = (const int*)d_in[3];
    float* out = (float*)d_out;

    const int mode = (out_size >= 2 * BWALK) ? 0 : 1;

    const size_t frag_bytes = (size_t)NSLOT * 8 * 64 * 16;           // 1 MB each
    const size_t off_Mlo = frag_bytes;
    const size_t off_A   = 2 * frag_bytes;
    const size_t need    = off_A + (size_t)BWALK * NE * NE * sizeof(float);  // 6 MB

    if (ws_size >= need) {
        uint4* MhiP = (uint4*)d_ws;
        uint4* MloP = (uint4*)((char*)d_ws + off_Mlo);
        float* A    = (float*)((char*)d_ws + off_A);

        hipLaunchKernelGGL(convert_m_kernel, dim3(NSLOT * 8 * 64 / 256), dim3(256), 0, stream,
                           Mup, Mdn, MhiP, MloP);
        hipLaunchKernelGGL(orbitals_kernel, dim3(NSLOT, BWALK / CHUNK), dim3(256), 0, stream,
                           y, R, MhiP, MloP, A);
        hipLaunchKernelGGL(lu_det_kernel, dim3(BWALK / 16), dim3(256), 0, stream,
                           A, out, mode);
    } else {
        hipLaunchKernelGGL(outputheaddet_kernel, dim3(BWALK), dim3(256), 0, stream,
                           y, Mup, Mdn, R, out, mode);
    }
}